// Round 1
// baseline (454.103 us; speedup 1.0000x reference)
//
#include <hip/hip_runtime.h>
#include <stdint.h>

// Problem constants (B=64, S=512 -> 32768 tokens)
#define N_TOK 32768
#define DIN   512
#define DFF   1024
#define MPAD  33792   // 32768 + 8*128 worst-case bucket padding

typedef __attribute__((ext_vector_type(8))) short bf16x8;
typedef __attribute__((ext_vector_type(4))) float f32x4;

__device__ __forceinline__ unsigned short f2bf(float f) {
    union { float f; unsigned int u; } v; v.f = f;
    unsigned int u = v.u;
    return (unsigned short)((u + 0x7FFFu + ((u >> 16) & 1u)) >> 16);
}
__device__ __forceinline__ float bf2f(unsigned int bits) {
    union { unsigned int u; float f; } v; v.u = bits << 16; return v.f;
}

// async 16B global -> LDS (wave-uniform LDS base + lane*16 pattern)
__device__ __forceinline__ void async16(const void* g, void* l) {
    __builtin_amdgcn_global_load_lds(
        (const __attribute__((address_space(1))) void*)g,
        (__attribute__((address_space(3))) void*)l, 16, 0, 0);
}

// ---------------- casts ----------------
__global__ void cast_x_kernel(const float* __restrict__ x,
                              unsigned short* __restrict__ out, int n) {
    int i = (blockIdx.x * 256 + threadIdx.x) * 4;
    if (i < n) {
        float4 v = *(const float4*)(x + i);
        ushort4 o;
        o.x = f2bf(v.x); o.y = f2bf(v.y); o.z = f2bf(v.z); o.w = f2bf(v.w);
        *(ushort4*)(out + i) = o;
    }
}

// [batch][K][N] f32 -> [batch][N][K] bf16 (weights become row-major in K)
__global__ void transpose_cast_kernel(const float* __restrict__ src,
                                      unsigned short* __restrict__ dst,
                                      int K, int N) {
    __shared__ float tile[32][33];
    int b = blockIdx.z;
    const float* s = src + (size_t)b * K * N;
    unsigned short* d = dst + (size_t)b * K * N;
    int n0 = blockIdx.x * 32, k0 = blockIdx.y * 32;
    for (int i = threadIdx.y; i < 32; i += 8)
        tile[i][threadIdx.x] = s[(size_t)(k0 + i) * N + n0 + threadIdx.x];
    __syncthreads();
    for (int i = threadIdx.y; i < 32; i += 8)
        d[(size_t)(n0 + i) * K + k0 + threadIdx.x] = f2bf(tile[threadIdx.x][i]);
}

// ---------------- bucketing (counting sort by type, pad to 128) ----------------
__global__ void perm_init_kernel(int* __restrict__ perm, int n) {
    int i = blockIdx.x * 256 + threadIdx.x;
    if (i < n) perm[i] = -1;
}

__global__ void bucket_count_kernel(const int* __restrict__ types,
                                    int* __restrict__ po, int* __restrict__ fill) {
    __shared__ int cnt[8];
    int tid = threadIdx.x;
    if (tid < 8) cnt[tid] = 0;
    __syncthreads();
    int lane = tid & 63;
    unsigned long long lt = (1ull << lane) - 1ull;
    for (int j = 0; j < N_TOK / 256; j++) {       // uniform trip count: ballots safe
        int t = types[tid + j * 256];
        #pragma unroll
        for (int b = 0; b < 8; b++) {
            unsigned long long m = __ballot(t == b);
            if ((t == b) && __popcll(m & lt) == 0)
                atomicAdd(&cnt[b], __popcll(m));
        }
    }
    __syncthreads();
    if (tid == 0) {
        int off = 0;
        #pragma unroll
        for (int b = 0; b < 8; b++) {
            po[b] = off; fill[b] = off;
            off += ((cnt[b] + 127) >> 7) << 7;    // pad bucket to multiple of 128
        }
        po[8] = off;
    }
}

__global__ void scatter_kernel(const int* __restrict__ types,
                               int* __restrict__ fill, int* __restrict__ perm) {
    int i = blockIdx.x * 256 + threadIdx.x;      // grid exactly covers N_TOK
    int lane = threadIdx.x & 63;
    unsigned long long lt = (1ull << lane) - 1ull;
    int t = types[i];
    #pragma unroll
    for (int b = 0; b < 8; b++) {
        unsigned long long m = __ballot(t == b);
        if (t == b) {
            int leader = __ffsll((unsigned long long)m) - 1;
            int base = 0;
            if (lane == leader) base = atomicAdd(&fill[b], __popcll(m));
            base = __shfl(base, leader);
            perm[base + __popcll(m & lt)] = i;
        }
    }
}

// ---------------- main GEMM: 128x128 tile, BK=64, 4 waves, 4x4 16x16x32 MFMA ----------------
// MODE 0: C = relu(A@B)        bf16 out, ldC
// MODE 1: rows gathered via perm, B selected per bucket; C[tok] = bf16(x[tok] + relu(acc))
// MODE 2: same as 0
template <int MODE>
__global__ __launch_bounds__(256, 2)
void gemm_kernel(const unsigned short* __restrict__ A,
                 const unsigned short* __restrict__ B,
                 unsigned short* __restrict__ C,
                 const float* __restrict__ xres,
                 const int* __restrict__ perm,
                 const int* __restrict__ po,
                 int K, int ldA, int ldC) {
    __shared__ unsigned short As[128 * 64];
    __shared__ unsigned short Bs[128 * 64];
    __shared__ int perm_tile[128];

    const int tid  = threadIdx.x;
    const int wave = tid >> 6;
    const int lane = tid & 63;
    const int m0 = blockIdx.y * 128;
    const int n0 = blockIdx.x * 128;
    const int wm = (wave & 1) * 64;
    const int wn = (wave >> 1) * 64;

    const unsigned short* Bp = B;
    if constexpr (MODE == 1) {
        int b = 0;
        #pragma unroll
        for (int i = 1; i < 8; i++) b += (m0 >= po[i]) ? 1 : 0;
        Bp = B + (size_t)b * (DIN * DFF);
        if (tid < 128) perm_tile[tid] = perm[m0 + tid];
        __syncthreads();
    }

    f32x4 acc[4][4];
    #pragma unroll
    for (int i = 0; i < 4; i++)
        #pragma unroll
        for (int j = 0; j < 4; j++)
            acc[i][j] = (f32x4){0.f, 0.f, 0.f, 0.f};

    for (int k0 = 0; k0 < K; k0 += 64) {
        __syncthreads();
        // stage A tile [128][64] : 1024 x 16B chunks, 4 per thread
        #pragma unroll
        for (int i = 0; i < 4; i++) {
            const int c   = (i * 4 + wave) * 64 + lane;
            const int row = c >> 3;
            const int col = (c & 7) << 3;
            size_t arow;
            if constexpr (MODE == 1) {
                int tok = perm_tile[row];
                arow = (size_t)(tok < 0 ? 0 : tok);   // pad rows: load token 0, skip store later
            } else {
                arow = (size_t)(m0 + row);
            }
            async16(A + arow * ldA + k0 + col, (char*)As + (size_t)c * 16);
        }
        // stage B tile [128][64]
        #pragma unroll
        for (int i = 0; i < 4; i++) {
            const int c   = (i * 4 + wave) * 64 + lane;
            const int row = c >> 3;
            const int col = (c & 7) << 3;
            async16(Bp + (size_t)(n0 + row) * K + k0 + col, (char*)Bs + (size_t)c * 16);
        }
        __syncthreads();   // compiler drains vmcnt before s_barrier

        #pragma unroll
        for (int ks = 0; ks < 2; ks++) {
            bf16x8 af[4], bfr[4];
            const int kk = ks * 32 + (lane >> 4) * 8;
            #pragma unroll
            for (int t = 0; t < 4; t++)
                af[t] = *(const bf16x8*)(As + (wm + t * 16 + (lane & 15)) * 64 + kk);
            #pragma unroll
            for (int t = 0; t < 4; t++)
                bfr[t] = *(const bf16x8*)(Bs + (wn + t * 16 + (lane & 15)) * 64 + kk);
            #pragma unroll
            for (int mt = 0; mt < 4; mt++)
                #pragma unroll
                for (int nt = 0; nt < 4; nt++)
                    acc[mt][nt] = __builtin_amdgcn_mfma_f32_16x16x32_bf16(
                        af[mt], bfr[nt], acc[mt][nt], 0, 0, 0);
        }
    }

    // epilogue: C/D layout col=lane&15, row=(lane>>4)*4+i
    #pragma unroll
    for (int mt = 0; mt < 4; mt++) {
        #pragma unroll
        for (int i = 0; i < 4; i++) {
            const int r = wm + mt * 16 + (lane >> 4) * 4 + i;
            int tok = 0;
            if constexpr (MODE == 1) {
                tok = perm_tile[r];
                if (tok < 0) continue;
            }
            #pragma unroll
            for (int nt = 0; nt < 4; nt++) {
                const int cc = n0 + wn + nt * 16 + (lane & 15);
                float v = fmaxf(acc[mt][nt][i], 0.f);
                if constexpr (MODE == 1) {
                    float res = xres[(size_t)tok * DIN + cc] + v;
                    C[(size_t)tok * DIN + cc] = f2bf(res);
                } else {
                    C[(size_t)(m0 + r) * ldC + cc] = f2bf(v);
                }
            }
        }
    }
}

// ---------------- final GEMV: out[n] = h[n,:] @ w2 ----------------
__global__ void gemv_kernel(const unsigned short* __restrict__ H,
                            const float* __restrict__ w2,
                            float* __restrict__ out) {
    const int tid  = threadIdx.x;
    const int wave = tid >> 6;
    const int lane = tid & 63;
    const int row  = blockIdx.x * 4 + wave;
    const unsigned short* h = H + (size_t)row * DIN + lane * 8;
    uint4 q = *(const uint4*)h;                       // 8 bf16
    float4 wa = *(const float4*)(w2 + lane * 8);
    float4 wb = *(const float4*)(w2 + lane * 8 + 4);
    float s = 0.f;
    s += bf2f(q.x & 0xFFFFu) * wa.x + bf2f(q.x >> 16) * wa.y;
    s += bf2f(q.y & 0xFFFFu) * wa.z + bf2f(q.y >> 16) * wa.w;
    s += bf2f(q.z & 0xFFFFu) * wb.x + bf2f(q.z >> 16) * wb.y;
    s += bf2f(q.w & 0xFFFFu) * wb.z + bf2f(q.w >> 16) * wb.w;
    #pragma unroll
    for (int o = 32; o > 0; o >>= 1) s += __shfl_down(s, o);
    if (lane == 0) out[row] = s;
}

extern "C" void kernel_launch(void* const* d_in, const int* in_sizes, int n_in,
                              void* d_out, int out_size, void* d_ws, size_t ws_size,
                              hipStream_t stream) {
    const float* x      = (const float*)d_in[0];
    const int*   types  = (const int*)d_in[1];
    const float* W_pre  = (const float*)d_in[2];
    const float* W_types= (const float*)d_in[3];
    const float* W_c1   = (const float*)d_in[4];
    const float* W_c2   = (const float*)d_in[5];
    float* out = (float*)d_out;

    // workspace layout (~106 MB):
    //  [0,32MB)    Xb   : x cast to bf16 [32768][512]; reused after GEMM1 as X_res
    //  [32,96MB)   Xff  : x_ = relu(x@W_pre) bf16 [32768][1024]; reused after GEMM2 as H (first 32MB)
    //  then transposed bf16 weights, perm, bucket offsets
    char* ws = (char*)d_ws;
    unsigned short* Xb  = (unsigned short*)(ws);
    unsigned short* Xff = (unsigned short*)(ws + 33554432ull);
    unsigned short* WpT = (unsigned short*)(ws + 100663296ull);            // 1 MB
    unsigned short* WtT = (unsigned short*)(ws + 101711872ull);            // 8 MB
    unsigned short* WcT = (unsigned short*)(ws + 110100480ull);            // 0.5 MB
    int* perm           = (int*)(ws + 110624768ull);                        // MPAD ints
    int* po             = (int*)(ws + 110759936ull);                        // 9 ints
    int* fill           = po + 16;                                          // 8 ints

    cast_x_kernel<<<N_TOK * DIN / 1024, 256, 0, stream>>>(x, Xb, N_TOK * DIN);
    transpose_cast_kernel<<<dim3(32, 16, 1), dim3(32, 8), 0, stream>>>(W_pre,   WpT, 512, 1024);
    transpose_cast_kernel<<<dim3(16, 32, 8), dim3(32, 8), 0, stream>>>(W_types, WtT, 1024, 512);
    transpose_cast_kernel<<<dim3(16, 16, 1), dim3(32, 8), 0, stream>>>(W_c1,    WcT, 512, 512);
    perm_init_kernel<<<MPAD / 256, 256, 0, stream>>>(perm, MPAD);
    bucket_count_kernel<<<1, 256, 0, stream>>>(types, po, fill);
    scatter_kernel<<<N_TOK / 256, 256, 0, stream>>>(types, fill, perm);

    // GEMM1: Xff = relu(Xb @ W_pre)      [32768,512]x[512,1024]
    gemm_kernel<0><<<dim3(DFF / 128, N_TOK / 128), 256, 0, stream>>>(
        Xb, WpT, Xff, nullptr, nullptr, nullptr, 512, 512, 1024);
    // GEMM2 (routed): Xb = bf16(x + relu(Xff[perm] @ W_types[bucket]))
    gemm_kernel<1><<<dim3(DIN / 128, MPAD / 128), 256, 0, stream>>>(
        Xff, WtT, Xb, x, perm, po, 1024, 1024, 512);
    // GEMM3: H(=Xff) = relu(Xb @ W_c1)   [32768,512]x[512,512]
    gemm_kernel<2><<<dim3(DIN / 128, N_TOK / 128), 256, 0, stream>>>(
        Xb, WcT, Xff, nullptr, nullptr, nullptr, 512, 512, 512);
    // out = H @ W_c2
    gemv_kernel<<<N_TOK / 4, 256, 0, stream>>>(Xff, W_c2, out);
}

// Round 2
// 351.171 us; speedup vs baseline: 1.2931x; 1.2931x over previous
//
#include <hip/hip_runtime.h>
#include <stdint.h>

// Problem constants (B=64, S=512 -> 32768 tokens)
#define N_TOK 32768
#define DIN   512
#define DFF   1024
#define MPAD  33792   // 32768 + 8*128 worst-case bucket padding

typedef __attribute__((ext_vector_type(8))) short bf16x8;
typedef __attribute__((ext_vector_type(4))) float f32x4;

__device__ __forceinline__ unsigned short f2bf(float f) {
    union { float f; unsigned int u; } v; v.f = f;
    unsigned int u = v.u;
    return (unsigned short)((u + 0x7FFFu + ((u >> 16) & 1u)) >> 16);
}
__device__ __forceinline__ float bf2f(unsigned int bits) {
    union { unsigned int u; float f; } v; v.u = bits << 16; return v.f;
}

// async 16B global -> LDS (wave-uniform LDS base + lane*16 pattern)
__device__ __forceinline__ void async16(const void* g, void* l) {
    __builtin_amdgcn_global_load_lds(
        (const __attribute__((address_space(1))) void*)g,
        (__attribute__((address_space(3))) void*)l, 16, 0, 0);
}

// ---------------- casts ----------------
__global__ void cast_x_kernel(const float* __restrict__ x,
                              unsigned short* __restrict__ out, int n) {
    int i = (blockIdx.x * 256 + threadIdx.x) * 4;
    if (i < n) {
        float4 v = *(const float4*)(x + i);
        ushort4 o;
        o.x = f2bf(v.x); o.y = f2bf(v.y); o.z = f2bf(v.z); o.w = f2bf(v.w);
        *(ushort4*)(out + i) = o;
    }
}

// [batch][K][N] f32 -> [batch][N][K] bf16 (weights become row-major in K)
__global__ void transpose_cast_kernel(const float* __restrict__ src,
                                      unsigned short* __restrict__ dst,
                                      int K, int N) {
    __shared__ float tile[32][33];
    int b = blockIdx.z;
    const float* s = src + (size_t)b * K * N;
    unsigned short* d = dst + (size_t)b * K * N;
    int n0 = blockIdx.x * 32, k0 = blockIdx.y * 32;
    for (int i = threadIdx.y; i < 32; i += 8)
        tile[i][threadIdx.x] = s[(size_t)(k0 + i) * N + n0 + threadIdx.x];
    __syncthreads();
    for (int i = threadIdx.y; i < 32; i += 8)
        d[(size_t)(n0 + i) * K + k0 + threadIdx.x] = f2bf(tile[threadIdx.x][i]);
}

// ---------------- bucketing (counting sort by type, pad to 128) ----------------
// perm -> -1, global counters -> 0
__global__ void perm_init_kernel(int* __restrict__ perm, int n, int* __restrict__ cnt) {
    int i = blockIdx.x * 256 + threadIdx.x;
    if (i < n) perm[i] = -1;
    if (blockIdx.x == 0 && threadIdx.x < 8) cnt[threadIdx.x] = 0;
}

// parallel histogram: 64 blocks x 256 threads, LDS histo -> global atomics
__global__ void histogram_kernel(const int* __restrict__ types, int* __restrict__ cnt) {
    __shared__ int lc[8];
    int tid = threadIdx.x;
    if (tid < 8) lc[tid] = 0;
    __syncthreads();
    int base = blockIdx.x * 512;               // 64 blocks * 512 = 32768
    #pragma unroll
    for (int j = 0; j < 2; j++)
        atomicAdd(&lc[types[base + j * 256 + tid]], 1);
    __syncthreads();
    if (tid < 8) atomicAdd(&cnt[tid], lc[tid]);
}

// single-wave prefix: bucket offsets padded to multiple of 128
__global__ void offsets_kernel(const int* __restrict__ cnt,
                               int* __restrict__ po, int* __restrict__ fill) {
    if (threadIdx.x == 0) {
        int off = 0;
        #pragma unroll
        for (int b = 0; b < 8; b++) {
            po[b] = off; fill[b] = off;
            off += ((cnt[b] + 127) >> 7) << 7;
        }
        po[8] = off;
    }
}

__global__ void scatter_kernel(const int* __restrict__ types,
                               int* __restrict__ fill, int* __restrict__ perm) {
    int i = blockIdx.x * 256 + threadIdx.x;      // grid exactly covers N_TOK
    int lane = threadIdx.x & 63;
    unsigned long long lt = (1ull << lane) - 1ull;
    int t = types[i];
    #pragma unroll
    for (int b = 0; b < 8; b++) {
        unsigned long long m = __ballot(t == b);
        if (t == b) {
            int leader = __ffsll((unsigned long long)m) - 1;
            int base = 0;
            if (lane == leader) base = atomicAdd(&fill[b], __popcll(m));
            base = __shfl(base, leader);
            perm[base + __popcll(m & lt)] = i;
        }
    }
}

// ---------------- main GEMM: 128x128 tile, BK=64, 4 waves, 4x4 16x16x32 MFMA ----------------
// MODE 0: C = relu(A@B)        bf16 out, ldC
// MODE 1: rows gathered via perm, B selected per bucket; C[tok] = bf16(x[tok] + relu(acc))
// MODE 2: same as 0
template <int MODE>
__global__ __launch_bounds__(256, 2)
void gemm_kernel(const unsigned short* __restrict__ A,
                 const unsigned short* __restrict__ B,
                 unsigned short* __restrict__ C,
                 const float* __restrict__ xres,
                 const int* __restrict__ perm,
                 const int* __restrict__ po,
                 int K, int ldA, int ldC) {
    __shared__ unsigned short As[128 * 64];
    __shared__ unsigned short Bs[128 * 64];
    __shared__ int perm_tile[128];

    const int tid  = threadIdx.x;
    const int wave = tid >> 6;
    const int lane = tid & 63;
    const int m0 = blockIdx.y * 128;
    const int n0 = blockIdx.x * 128;
    const int wm = (wave & 1) * 64;
    const int wn = (wave >> 1) * 64;

    const unsigned short* Bp = B;
    if constexpr (MODE == 1) {
        int b = 0;
        #pragma unroll
        for (int i = 1; i < 8; i++) b += (m0 >= po[i]) ? 1 : 0;
        Bp = B + (size_t)b * (DIN * DFF);
        if (tid < 128) perm_tile[tid] = perm[m0 + tid];
        __syncthreads();
    }

    f32x4 acc[4][4];
    #pragma unroll
    for (int i = 0; i < 4; i++)
        #pragma unroll
        for (int j = 0; j < 4; j++)
            acc[i][j] = (f32x4){0.f, 0.f, 0.f, 0.f};

    for (int k0 = 0; k0 < K; k0 += 64) {
        __syncthreads();
        // stage A tile [128][64] : 1024 x 16B chunks, 4 per thread
        #pragma unroll
        for (int i = 0; i < 4; i++) {
            const int c   = (i * 4 + wave) * 64 + lane;
            const int row = c >> 3;
            const int col = (c & 7) << 3;
            size_t arow;
            if constexpr (MODE == 1) {
                int tok = perm_tile[row];
                arow = (size_t)(tok < 0 ? 0 : tok);   // pad rows: load token 0, skip store later
            } else {
                arow = (size_t)(m0 + row);
            }
            async16(A + arow * ldA + k0 + col, (char*)As + (size_t)c * 16);
        }
        // stage B tile [128][64]
        #pragma unroll
        for (int i = 0; i < 4; i++) {
            const int c   = (i * 4 + wave) * 64 + lane;
            const int row = c >> 3;
            const int col = (c & 7) << 3;
            async16(Bp + (size_t)(n0 + row) * K + k0 + col, (char*)Bs + (size_t)c * 16);
        }
        __syncthreads();   // compiler drains vmcnt before s_barrier

        #pragma unroll
        for (int ks = 0; ks < 2; ks++) {
            bf16x8 af[4], bfr[4];
            const int kk = ks * 32 + (lane >> 4) * 8;
            #pragma unroll
            for (int t = 0; t < 4; t++)
                af[t] = *(const bf16x8*)(As + (wm + t * 16 + (lane & 15)) * 64 + kk);
            #pragma unroll
            for (int t = 0; t < 4; t++)
                bfr[t] = *(const bf16x8*)(Bs + (wn + t * 16 + (lane & 15)) * 64 + kk);
            #pragma unroll
            for (int mt = 0; mt < 4; mt++)
                #pragma unroll
                for (int nt = 0; nt < 4; nt++)
                    acc[mt][nt] = __builtin_amdgcn_mfma_f32_16x16x32_bf16(
                        af[mt], bfr[nt], acc[mt][nt], 0, 0, 0);
        }
    }

    // epilogue: C/D layout col=lane&15, row=(lane>>4)*4+i
    #pragma unroll
    for (int mt = 0; mt < 4; mt++) {
        #pragma unroll
        for (int i = 0; i < 4; i++) {
            const int r = wm + mt * 16 + (lane >> 4) * 4 + i;
            int tok = 0;
            if constexpr (MODE == 1) {
                tok = perm_tile[r];
                if (tok < 0) continue;
            }
            #pragma unroll
            for (int nt = 0; nt < 4; nt++) {
                const int cc = n0 + wn + nt * 16 + (lane & 15);
                float v = fmaxf(acc[mt][nt][i], 0.f);
                if constexpr (MODE == 1) {
                    float res = xres[(size_t)tok * DIN + cc] + v;
                    C[(size_t)tok * DIN + cc] = f2bf(res);
                } else {
                    C[(size_t)(m0 + r) * ldC + cc] = f2bf(v);
                }
            }
        }
    }
}

// ---------------- final GEMV: out[n] = h[n,:] @ w2 ----------------
__global__ void gemv_kernel(const unsigned short* __restrict__ H,
                            const float* __restrict__ w2,
                            float* __restrict__ out) {
    const int tid  = threadIdx.x;
    const int wave = tid >> 6;
    const int lane = tid & 63;
    const int row  = blockIdx.x * 4 + wave;
    const unsigned short* h = H + (size_t)row * DIN + lane * 8;
    uint4 q = *(const uint4*)h;                       // 8 bf16
    float4 wa = *(const float4*)(w2 + lane * 8);
    float4 wb = *(const float4*)(w2 + lane * 8 + 4);
    float s = 0.f;
    s += bf2f(q.x & 0xFFFFu) * wa.x + bf2f(q.x >> 16) * wa.y;
    s += bf2f(q.y & 0xFFFFu) * wa.z + bf2f(q.y >> 16) * wa.w;
    s += bf2f(q.z & 0xFFFFu) * wb.x + bf2f(q.z >> 16) * wb.y;
    s += bf2f(q.w & 0xFFFFu) * wb.z + bf2f(q.w >> 16) * wb.w;
    #pragma unroll
    for (int o = 32; o > 0; o >>= 1) s += __shfl_down(s, o);
    if (lane == 0) out[row] = s;
}

extern "C" void kernel_launch(void* const* d_in, const int* in_sizes, int n_in,
                              void* d_out, int out_size, void* d_ws, size_t ws_size,
                              hipStream_t stream) {
    const float* x      = (const float*)d_in[0];
    const int*   types  = (const int*)d_in[1];
    const float* W_pre  = (const float*)d_in[2];
    const float* W_types= (const float*)d_in[3];
    const float* W_c1   = (const float*)d_in[4];
    const float* W_c2   = (const float*)d_in[5];
    float* out = (float*)d_out;

    // workspace layout (~106 MB):
    //  [0,32MB)    Xb   : x cast to bf16 [32768][512]; reused after GEMM2 as X_res
    //  [32,96MB)   Xff  : x_ = relu(x@W_pre) bf16 [32768][1024]; reused after GEMM2 as H
    //  then transposed bf16 weights, perm, bucket offsets, counters
    char* ws = (char*)d_ws;
    unsigned short* Xb  = (unsigned short*)(ws);
    unsigned short* Xff = (unsigned short*)(ws + 33554432ull);
    unsigned short* WpT = (unsigned short*)(ws + 100663296ull);            // 1 MB
    unsigned short* WtT = (unsigned short*)(ws + 101711872ull);            // 8 MB
    unsigned short* WcT = (unsigned short*)(ws + 110100480ull);            // 0.5 MB
    int* perm           = (int*)(ws + 110624768ull);                        // MPAD ints
    int* po             = (int*)(ws + 110759936ull);                        // 9 ints
    int* fill           = po + 16;                                          // 8 ints
    int* cnt            = po + 32;                                          // 8 ints

    cast_x_kernel<<<N_TOK * DIN / 1024, 256, 0, stream>>>(x, Xb, N_TOK * DIN);
    transpose_cast_kernel<<<dim3(32, 16, 1), dim3(32, 8), 0, stream>>>(W_pre,   WpT, 512, 1024);
    transpose_cast_kernel<<<dim3(16, 32, 8), dim3(32, 8), 0, stream>>>(W_types, WtT, 1024, 512);
    transpose_cast_kernel<<<dim3(16, 16, 1), dim3(32, 8), 0, stream>>>(W_c1,    WcT, 512, 512);
    perm_init_kernel<<<MPAD / 256, 256, 0, stream>>>(perm, MPAD, cnt);
    histogram_kernel<<<64, 256, 0, stream>>>(types, cnt);
    offsets_kernel<<<1, 64, 0, stream>>>(cnt, po, fill);
    scatter_kernel<<<N_TOK / 256, 256, 0, stream>>>(types, fill, perm);

    // GEMM1: Xff = relu(Xb @ W_pre)      [32768,512]x[512,1024]
    gemm_kernel<0><<<dim3(DFF / 128, N_TOK / 128), 256, 0, stream>>>(
        Xb, WpT, Xff, nullptr, nullptr, nullptr, 512, 512, 1024);
    // GEMM2 (routed): Xb = bf16(x + relu(Xff[perm] @ W_types[bucket]))
    gemm_kernel<1><<<dim3(DIN / 128, MPAD / 128), 256, 0, stream>>>(
        Xff, WtT, Xb, x, perm, po, 1024, 1024, 512);
    // GEMM3: H(=Xff) = relu(Xb @ W_c1)   [32768,512]x[512,512]
    gemm_kernel<2><<<dim3(DIN / 128, N_TOK / 128), 256, 0, stream>>>(
        Xb, WcT, Xff, nullptr, nullptr, nullptr, 512, 512, 512);
    // out = H @ W_c2
    gemv_kernel<<<N_TOK / 4, 256, 0, stream>>>(Xff, W_c2, out);
}

// Round 3
// 329.216 us; speedup vs baseline: 1.3793x; 1.0667x over previous
//
#include <hip/hip_runtime.h>
#include <stdint.h>

// Problem constants (B=64, S=512 -> 32768 tokens)
#define N_TOK 32768
#define DIN   512
#define DFF   1024
#define MPAD  33792   // 32768 + 8*128 worst-case bucket padding

typedef __attribute__((ext_vector_type(8))) short bf16x8;
typedef __attribute__((ext_vector_type(4))) float f32x4;

__device__ __forceinline__ unsigned short f2bf(float f) {
    union { float f; unsigned int u; } v; v.f = f;
    unsigned int u = v.u;
    return (unsigned short)((u + 0x7FFFu + ((u >> 16) & 1u)) >> 16);
}
__device__ __forceinline__ float bf2f(unsigned int bits) {
    union { unsigned int u; float f; } v; v.u = bits << 16; return v.f;
}

// async 16B global -> LDS (wave-uniform LDS base + lane*16 pattern)
__device__ __forceinline__ void async16(const void* g, void* l) {
    __builtin_amdgcn_global_load_lds(
        (const __attribute__((address_space(1))) void*)g,
        (__attribute__((address_space(3))) void*)l, 16, 0, 0);
}

// ---------------- casts ----------------
__global__ void cast_x_kernel(const float* __restrict__ x,
                              unsigned short* __restrict__ out, int n) {
    int i = (blockIdx.x * 256 + threadIdx.x) * 4;
    if (i < n) {
        float4 v = *(const float4*)(x + i);
        ushort4 o;
        o.x = f2bf(v.x); o.y = f2bf(v.y); o.z = f2bf(v.z); o.w = f2bf(v.w);
        *(ushort4*)(out + i) = o;
    }
}

// [batch][K][N] f32 -> [batch][N][K] bf16 (weights become row-major in K)
__global__ void transpose_cast_kernel(const float* __restrict__ src,
                                      unsigned short* __restrict__ dst,
                                      int K, int N) {
    __shared__ float tile[32][33];
    int b = blockIdx.z;
    const float* s = src + (size_t)b * K * N;
    unsigned short* d = dst + (size_t)b * K * N;
    int n0 = blockIdx.x * 32, k0 = blockIdx.y * 32;
    for (int i = threadIdx.y; i < 32; i += 8)
        tile[i][threadIdx.x] = s[(size_t)(k0 + i) * N + n0 + threadIdx.x];
    __syncthreads();
    for (int i = threadIdx.y; i < 32; i += 8)
        d[(size_t)(n0 + i) * K + k0 + threadIdx.x] = f2bf(tile[threadIdx.x][i]);
}

// ---------------- bucketing (counting sort by type, pad to 128) ----------------
// perm -> -1, global counters -> 0
__global__ void perm_init_kernel(int* __restrict__ perm, int n, int* __restrict__ cnt) {
    int i = blockIdx.x * 256 + threadIdx.x;
    if (i < n) perm[i] = -1;
    if (blockIdx.x == 0 && threadIdx.x < 8) cnt[threadIdx.x] = 0;
}

// parallel histogram: 64 blocks x 256 threads, LDS histo -> global atomics
__global__ void histogram_kernel(const int* __restrict__ types, int* __restrict__ cnt) {
    __shared__ int lc[8];
    int tid = threadIdx.x;
    if (tid < 8) lc[tid] = 0;
    __syncthreads();
    int base = blockIdx.x * 512;               // 64 blocks * 512 = 32768
    #pragma unroll
    for (int j = 0; j < 2; j++)
        atomicAdd(&lc[types[base + j * 256 + tid]], 1);
    __syncthreads();
    if (tid < 8) atomicAdd(&cnt[tid], lc[tid]);
}

// single-wave prefix: bucket offsets padded to multiple of 128
__global__ void offsets_kernel(const int* __restrict__ cnt,
                               int* __restrict__ po, int* __restrict__ fill) {
    if (threadIdx.x == 0) {
        int off = 0;
        #pragma unroll
        for (int b = 0; b < 8; b++) {
            po[b] = off; fill[b] = off;
            off += ((cnt[b] + 127) >> 7) << 7;
        }
        po[8] = off;
    }
}

// scatter token ids into buckets; also zero the fp32 output (atomicAdd target)
__global__ void scatter_kernel(const int* __restrict__ types,
                               int* __restrict__ fill, int* __restrict__ perm,
                               float* __restrict__ outz) {
    int i = blockIdx.x * 256 + threadIdx.x;      // grid exactly covers N_TOK
    outz[i] = 0.f;
    int lane = threadIdx.x & 63;
    unsigned long long lt = (1ull << lane) - 1ull;
    int t = types[i];
    #pragma unroll
    for (int b = 0; b < 8; b++) {
        unsigned long long m = __ballot(t == b);
        if (t == b) {
            int leader = __ffsll((unsigned long long)m) - 1;
            int base = 0;
            if (lane == leader) base = atomicAdd(&fill[b], __popcll(m));
            base = __shfl(base, leader);
            perm[base + __popcll(m & lt)] = i;
        }
    }
}

// ---------------- main GEMM: 128x128 tile, BK=64, 4 waves, 4x4 16x16x32 MFMA ----
// LDS tiles are XOR-swizzled: LDS slot (row, jj) holds global chunk (row, jj^(row&7)),
// so quad reads spread across all 32 banks (kills the 16-way row-stride conflict).
// MFMA operands are SWAPPED: acc = mfma(bfr, af) -> D[n][tok]:
//   n   = quad*4 + reg  (4 consecutive columns per lane -> 8B vector epilogue)
//   tok = lane & 15
// MODE 0: C = relu(A@B), ushort4 stores
// MODE 1: rows gathered via perm, B selected per bucket;
//         C[tok] = bf16(xres_bf16[tok] + relu(acc))   (read-modify-write, same elem)
// MODE 2: fused head: out[tok] += relu(A@B) . w2  (partial per n-block, atomicAdd)
template <int MODE>
__global__ __launch_bounds__(256, 4)
void gemm_kernel(const unsigned short* __restrict__ A,
                 const unsigned short* __restrict__ B,
                 unsigned short* __restrict__ C,
                 const unsigned short* __restrict__ xres,
                 const int* __restrict__ perm,
                 const int* __restrict__ po,
                 const float* __restrict__ w2,
                 float* __restrict__ outp,
                 int K, int ldA, int ldC) {
    __shared__ unsigned short As[128 * 64];
    __shared__ unsigned short Bs[128 * 64];
    __shared__ int perm_tile[128];

    const int tid  = threadIdx.x;
    const int wave = tid >> 6;
    const int lane = tid & 63;
    const int quad = lane >> 4;
    const int tl   = lane & 15;
    const int m0 = blockIdx.y * 128;
    const int n0 = blockIdx.x * 128;
    const int wm = (wave & 1) * 64;
    const int wn = (wave >> 1) * 64;

    const unsigned short* Bp = B;
    if constexpr (MODE == 1) {
        int b = 0;
        #pragma unroll
        for (int i = 1; i < 8; i++) b += (m0 >= po[i]) ? 1 : 0;
        Bp = B + (size_t)b * (DIN * DFF);
        if (tid < 128) perm_tile[tid] = perm[m0 + tid];
    }

    f32x4 acc[4][4];
    #pragma unroll
    for (int i = 0; i < 4; i++)
        #pragma unroll
        for (int j = 0; j < 4; j++)
            acc[i][j] = (f32x4){0.f, 0.f, 0.f, 0.f};

    for (int k0 = 0; k0 < K; k0 += 64) {
        __syncthreads();
        // stage A tile [128][64] : 1024 x 16B chunks, 4 per thread, XOR-swizzled
        #pragma unroll
        for (int i = 0; i < 4; i++) {
            const int c   = (i * 4 + wave) * 64 + lane;
            const int row = c >> 3;
            const int gj  = (c & 7) ^ (row & 7);     // swizzled source chunk
            size_t arow;
            if constexpr (MODE == 1) {
                int tok = perm_tile[row];
                arow = (size_t)(tok < 0 ? 0 : tok);  // pad rows: load token 0, skip store later
            } else {
                arow = (size_t)(m0 + row);
            }
            async16(A + arow * ldA + k0 + gj * 8, (char*)As + (size_t)c * 16);
        }
        // stage B tile [128][64], same swizzle
        #pragma unroll
        for (int i = 0; i < 4; i++) {
            const int c   = (i * 4 + wave) * 64 + lane;
            const int row = c >> 3;
            const int gj  = (c & 7) ^ (row & 7);
            async16(Bp + (size_t)(n0 + row) * K + k0 + gj * 8, (char*)Bs + (size_t)c * 16);
        }
        __syncthreads();

        #pragma unroll
        for (int ks = 0; ks < 2; ks++) {
            bf16x8 af[4], bfr[4];
            const int jc = ks * 4 + quad;            // logical 16B chunk index in row
            #pragma unroll
            for (int t = 0; t < 4; t++) {
                const int r = wm + t * 16 + tl;
                af[t] = *(const bf16x8*)(As + (r * 8 + (jc ^ (r & 7))) * 8);
            }
            #pragma unroll
            for (int t = 0; t < 4; t++) {
                const int r = wn + t * 16 + tl;
                bfr[t] = *(const bf16x8*)(Bs + (r * 8 + (jc ^ (r & 7))) * 8);
            }
            #pragma unroll
            for (int mt = 0; mt < 4; mt++)
                #pragma unroll
                for (int nt = 0; nt < 4; nt++)
                    acc[mt][nt] = __builtin_amdgcn_mfma_f32_16x16x32_bf16(
                        bfr[nt], af[mt], acc[mt][nt], 0, 0, 0);  // swapped: D[n][tok]
        }
    }

    // ---- epilogue: lane holds 4 consecutive n (regs) for token tl ----
    if constexpr (MODE == 2) {
        float4 w2v[4];
        #pragma unroll
        for (int nt = 0; nt < 4; nt++)
            w2v[nt] = *(const float4*)(w2 + n0 + wn + nt * 16 + quad * 4);
        #pragma unroll
        for (int mt = 0; mt < 4; mt++) {
            float s = 0.f;
            #pragma unroll
            for (int nt = 0; nt < 4; nt++) {
                s += fmaxf(acc[mt][nt][0], 0.f) * w2v[nt].x;
                s += fmaxf(acc[mt][nt][1], 0.f) * w2v[nt].y;
                s += fmaxf(acc[mt][nt][2], 0.f) * w2v[nt].z;
                s += fmaxf(acc[mt][nt][3], 0.f) * w2v[nt].w;
            }
            s += __shfl_down(s, 32);
            s += __shfl_down(s, 16);
            if (lane < 16) atomicAdd(&outp[m0 + wm + mt * 16 + lane], s);
        }
    } else {
        #pragma unroll
        for (int mt = 0; mt < 4; mt++) {
            size_t rowbase;
            if constexpr (MODE == 1) {
                int tok = perm_tile[wm + mt * 16 + tl];
                if (tok < 0) continue;
                rowbase = (size_t)tok * DIN;
            } else {
                rowbase = (size_t)(m0 + wm + mt * 16 + tl) * ldC;
            }
            #pragma unroll
            for (int nt = 0; nt < 4; nt++) {
                const int ncol = n0 + wn + nt * 16 + quad * 4;
                ushort4 o;
                if constexpr (MODE == 1) {
                    ushort4 rv = *(const ushort4*)(xres + rowbase + ncol);
                    o.x = f2bf(bf2f(rv.x) + fmaxf(acc[mt][nt][0], 0.f));
                    o.y = f2bf(bf2f(rv.y) + fmaxf(acc[mt][nt][1], 0.f));
                    o.z = f2bf(bf2f(rv.z) + fmaxf(acc[mt][nt][2], 0.f));
                    o.w = f2bf(bf2f(rv.w) + fmaxf(acc[mt][nt][3], 0.f));
                } else {
                    o.x = f2bf(fmaxf(acc[mt][nt][0], 0.f));
                    o.y = f2bf(fmaxf(acc[mt][nt][1], 0.f));
                    o.z = f2bf(fmaxf(acc[mt][nt][2], 0.f));
                    o.w = f2bf(fmaxf(acc[mt][nt][3], 0.f));
                }
                *(ushort4*)(C + rowbase + ncol) = o;
            }
        }
    }
}

extern "C" void kernel_launch(void* const* d_in, const int* in_sizes, int n_in,
                              void* d_out, int out_size, void* d_ws, size_t ws_size,
                              hipStream_t stream) {
    const float* x      = (const float*)d_in[0];
    const int*   types  = (const int*)d_in[1];
    const float* W_pre  = (const float*)d_in[2];
    const float* W_types= (const float*)d_in[3];
    const float* W_c1   = (const float*)d_in[4];
    const float* W_c2   = (const float*)d_in[5];
    float* out = (float*)d_out;

    // workspace layout:
    //  [0,32MB)    Xb   : x cast to bf16 [32768][512]; becomes X_res after GEMM2
    //  [32,96MB)   Xff  : x_ = relu(x@W_pre) bf16 [32768][1024]
    //  then transposed bf16 weights, perm, bucket offsets, counters
    char* ws = (char*)d_ws;
    unsigned short* Xb  = (unsigned short*)(ws);
    unsigned short* Xff = (unsigned short*)(ws + 33554432ull);
    unsigned short* WpT = (unsigned short*)(ws + 100663296ull);            // 1 MB
    unsigned short* WtT = (unsigned short*)(ws + 101711872ull);            // 8 MB
    unsigned short* WcT = (unsigned short*)(ws + 110100480ull);            // 0.5 MB
    int* perm           = (int*)(ws + 110624768ull);                        // MPAD ints
    int* po             = (int*)(ws + 110759936ull);                        // 9 ints
    int* fill           = po + 16;                                          // 8 ints
    int* cnt            = po + 32;                                          // 8 ints

    cast_x_kernel<<<N_TOK * DIN / 1024, 256, 0, stream>>>(x, Xb, N_TOK * DIN);
    transpose_cast_kernel<<<dim3(32, 16, 1), dim3(32, 8), 0, stream>>>(W_pre,   WpT, 512, 1024);
    transpose_cast_kernel<<<dim3(16, 32, 8), dim3(32, 8), 0, stream>>>(W_types, WtT, 1024, 512);
    transpose_cast_kernel<<<dim3(16, 16, 1), dim3(32, 8), 0, stream>>>(W_c1,    WcT, 512, 512);
    perm_init_kernel<<<MPAD / 256, 256, 0, stream>>>(perm, MPAD, cnt);
    histogram_kernel<<<64, 256, 0, stream>>>(types, cnt);
    offsets_kernel<<<1, 64, 0, stream>>>(cnt, po, fill);
    scatter_kernel<<<N_TOK / 256, 256, 0, stream>>>(types, fill, perm, out);

    // GEMM1: Xff = relu(Xb @ W_pre)      [32768,512]x[512,1024]
    gemm_kernel<0><<<dim3(DFF / 128, N_TOK / 128), 256, 0, stream>>>(
        Xb, WpT, Xff, nullptr, nullptr, nullptr, nullptr, nullptr, 512, 512, 1024);
    // GEMM2 (routed): Xb = bf16(Xb + relu(Xff[perm] @ W_types[bucket]))
    gemm_kernel<1><<<dim3(DIN / 128, MPAD / 128), 256, 0, stream>>>(
        Xff, WtT, Xb, Xb, perm, po, nullptr, nullptr, 1024, 1024, 512);
    // GEMM3 + GEMV fused: out = relu(Xb @ W_c1) @ W_c2   (partial dots, atomicAdd)
    gemm_kernel<2><<<dim3(DIN / 128, N_TOK / 128), 256, 0, stream>>>(
        Xb, WcT, nullptr, nullptr, nullptr, nullptr, W_c2, out, 512, 512, 512);
}

// Round 4
// 313.260 us; speedup vs baseline: 1.4496x; 1.0509x over previous
//
#include <hip/hip_runtime.h>
#include <stdint.h>

// Problem constants (B=64, S=512 -> 32768 tokens)
#define N_TOK 32768
#define DIN   512
#define DFF   1024
#define MPAD  33792   // 32768 + 8*128 worst-case bucket padding

typedef __attribute__((ext_vector_type(8))) short bf16x8;
typedef __attribute__((ext_vector_type(4))) float f32x4;

__device__ __forceinline__ unsigned short f2bf(float f) {
    union { float f; unsigned int u; } v; v.f = f;
    unsigned int u = v.u;
    return (unsigned short)((u + 0x7FFFu + ((u >> 16) & 1u)) >> 16);
}
__device__ __forceinline__ float bf2f(unsigned int bits) {
    union { unsigned int u; float f; } v; v.u = bits << 16; return v.f;
}

// async 16B global -> LDS (wave-uniform LDS base + lane*16 pattern)
__device__ __forceinline__ void async16(const void* g, void* l) {
    __builtin_amdgcn_global_load_lds(
        (const __attribute__((address_space(1))) void*)g,
        (__attribute__((address_space(3))) void*)l, 16, 0, 0);
}

// ---------------- fused weight prep: transpose+cast all weights, zero counters ----
// z=0: W_pre [512][1024]; z=1..8: W_types[z-1] [1024][512]; z=9: W_c1 [512][512]
__global__ void prep_weights_kernel(const float* __restrict__ Wp,
                                    const float* __restrict__ Wt,
                                    const float* __restrict__ Wc,
                                    unsigned short* __restrict__ WpT,
                                    unsigned short* __restrict__ WtT,
                                    unsigned short* __restrict__ WcT,
                                    int* __restrict__ cnt) {
    __shared__ float tile[32][33];
    const int z = blockIdx.z;
    if (z == 0 && blockIdx.x == 0 && blockIdx.y == 0 &&
        threadIdx.y == 0 && threadIdx.x < 8)
        cnt[threadIdx.x] = 0;
    const float* s; unsigned short* d; int K, N;
    if (z == 0)      { s = Wp;                        d = WpT;                        K = 512;  N = 1024; }
    else if (z <= 8) { s = Wt + (size_t)(z-1)*DIN*DFF; d = WtT + (size_t)(z-1)*DIN*DFF; K = 1024; N = 512; }
    else             { s = Wc;                        d = WcT;                        K = 512;  N = 512; }
    const int n0 = blockIdx.x * 32, k0 = blockIdx.y * 32;
    if (n0 >= N || k0 >= K) return;
    for (int i = threadIdx.y; i < 32; i += 8)
        tile[i][threadIdx.x] = s[(size_t)(k0 + i) * N + n0 + threadIdx.x];
    __syncthreads();
    for (int i = threadIdx.y; i < 32; i += 8)
        d[(size_t)(n0 + i) * K + k0 + threadIdx.x] = f2bf(tile[threadIdx.x][i]);
}

// ---------------- fused token prep: cast x -> bf16, histogram types, init perm ----
// 16384 blocks x 256 threads; blocks 0..63 also histogram, 64..195 init perm.
__global__ void prep_tokens_kernel(const float* __restrict__ x,
                                   unsigned short* __restrict__ Xb,
                                   const int* __restrict__ types,
                                   int* __restrict__ cnt,
                                   int* __restrict__ perm) {
    __shared__ int lc[8];
    const int blk = blockIdx.x, tid = threadIdx.x;
    const int i = blk * 1024 + tid * 4;
    float4 v = *(const float4*)(x + i);
    ushort4 o;
    o.x = f2bf(v.x); o.y = f2bf(v.y); o.z = f2bf(v.z); o.w = f2bf(v.w);
    *(ushort4*)(Xb + i) = o;
    if (blk < 64) {
        if (tid < 8) lc[tid] = 0;
        __syncthreads();
        atomicAdd(&lc[types[blk * 512 + tid]], 1);
        atomicAdd(&lc[types[blk * 512 + 256 + tid]], 1);
        __syncthreads();
        if (tid < 8) atomicAdd(&cnt[tid], lc[tid]);
    } else if (blk < 64 + MPAD / 256) {
        perm[(blk - 64) * 256 + tid] = -1;
    }
}

// single-wave prefix: bucket offsets padded to multiple of 128
__global__ void offsets_kernel(const int* __restrict__ cnt,
                               int* __restrict__ po, int* __restrict__ fill) {
    if (threadIdx.x == 0) {
        int off = 0;
        #pragma unroll
        for (int b = 0; b < 8; b++) {
            po[b] = off; fill[b] = off;
            off += ((cnt[b] + 127) >> 7) << 7;
        }
        po[8] = off;
    }
}

// scatter token ids into buckets; also zero the fp32 output (atomicAdd target)
__global__ void scatter_kernel(const int* __restrict__ types,
                               int* __restrict__ fill, int* __restrict__ perm,
                               float* __restrict__ outz) {
    int i = blockIdx.x * 256 + threadIdx.x;      // grid exactly covers N_TOK
    outz[i] = 0.f;
    int lane = threadIdx.x & 63;
    unsigned long long lt = (1ull << lane) - 1ull;
    int t = types[i];
    #pragma unroll
    for (int b = 0; b < 8; b++) {
        unsigned long long m = __ballot(t == b);
        if (t == b) {
            int leader = __ffsll((unsigned long long)m) - 1;
            int base = 0;
            if (lane == leader) base = atomicAdd(&fill[b], __popcll(m));
            base = __shfl(base, leader);
            perm[base + __popcll(m & lt)] = i;
        }
    }
}

// ------------- main GEMM: 128x256 (MxN) tile, BK=64, 512 thr / 8 waves ----------
// per-wave 64x64 via 4x4 16x16x32 MFMA. LDS XOR-swizzled (slot jj holds chunk
// jj^(row&7)) -> conflict-free quad reads. MFMA operands SWAPPED: D[n][tok]:
//   n = quad*4 + reg (4 consecutive cols/lane), tok = lane & 15
// MODE 0: C = relu(A@B), ushort4 stores
// MODE 1: rows gathered via perm, B selected per bucket;
//         C[tok] = bf16(xres_bf16[tok] + relu(acc))
// MODE 2: fused head: out[tok] += relu(A@B) . w2  (atomicAdd partials)
template <int MODE>
__global__ __launch_bounds__(512, 4)
void gemm_kernel(const unsigned short* __restrict__ A,
                 const unsigned short* __restrict__ B,
                 unsigned short* __restrict__ C,
                 const unsigned short* __restrict__ xres,
                 const int* __restrict__ perm,
                 const int* __restrict__ po,
                 const float* __restrict__ w2,
                 float* __restrict__ outp,
                 int K, int ldA, int ldC) {
    __shared__ unsigned short As[128 * 64];
    __shared__ unsigned short Bs[256 * 64];
    __shared__ int perm_tile[128];

    const int tid  = threadIdx.x;
    const int wave = tid >> 6;          // 0..7
    const int lane = tid & 63;
    const int quad = lane >> 4;
    const int tl   = lane & 15;
    const int m0 = blockIdx.y * 128;
    const int n0 = blockIdx.x * 256;
    const int wm = (wave & 1) * 64;     // {0,64}
    const int wn = (wave >> 1) * 64;    // {0,64,128,192}

    const unsigned short* Bp = B;
    if constexpr (MODE == 1) {
        int b = 0;
        #pragma unroll
        for (int i = 1; i < 8; i++) b += (m0 >= po[i]) ? 1 : 0;
        Bp = B + (size_t)b * (DIN * DFF);
        if (tid < 128) perm_tile[tid] = perm[m0 + tid];
    }

    f32x4 acc[4][4];
    #pragma unroll
    for (int i = 0; i < 4; i++)
        #pragma unroll
        for (int j = 0; j < 4; j++)
            acc[i][j] = (f32x4){0.f, 0.f, 0.f, 0.f};

    for (int k0 = 0; k0 < K; k0 += 64) {
        __syncthreads();
        // stage A tile [128][64]: 1024 x 16B chunks, 2/thread, XOR-swizzled
        #pragma unroll
        for (int i = 0; i < 2; i++) {
            const int c   = (i * 8 + wave) * 64 + lane;
            const int row = c >> 3;
            const int gj  = (c & 7) ^ (row & 7);
            size_t arow;
            if constexpr (MODE == 1) {
                int tok = perm_tile[row];
                arow = (size_t)(tok < 0 ? 0 : tok);
            } else {
                arow = (size_t)(m0 + row);
            }
            async16(A + arow * ldA + k0 + gj * 8, (char*)As + (size_t)c * 16);
        }
        // stage B tile [256][64]: 2048 chunks, 4/thread, same swizzle
        #pragma unroll
        for (int i = 0; i < 4; i++) {
            const int c   = (i * 8 + wave) * 64 + lane;
            const int row = c >> 3;
            const int gj  = (c & 7) ^ (row & 7);
            async16(Bp + (size_t)(n0 + row) * K + k0 + gj * 8, (char*)Bs + (size_t)c * 16);
        }
        __syncthreads();

        #pragma unroll
        for (int ks = 0; ks < 2; ks++) {
            bf16x8 af[4], bfr[4];
            const int jc = ks * 4 + quad;            // logical 16B chunk in row
            #pragma unroll
            for (int t = 0; t < 4; t++) {
                const int r = wm + t * 16 + tl;
                af[t] = *(const bf16x8*)(As + (r * 8 + (jc ^ (r & 7))) * 8);
            }
            #pragma unroll
            for (int t = 0; t < 4; t++) {
                const int r = wn + t * 16 + tl;
                bfr[t] = *(const bf16x8*)(Bs + (r * 8 + (jc ^ (r & 7))) * 8);
            }
            #pragma unroll
            for (int mt = 0; mt < 4; mt++)
                #pragma unroll
                for (int nt = 0; nt < 4; nt++)
                    acc[mt][nt] = __builtin_amdgcn_mfma_f32_16x16x32_bf16(
                        bfr[nt], af[mt], acc[mt][nt], 0, 0, 0);  // swapped: D[n][tok]
        }
    }

    // ---- epilogue: lane holds 4 consecutive n (regs) for token tl ----
    if constexpr (MODE == 2) {
        float4 w2v[4];
        #pragma unroll
        for (int nt = 0; nt < 4; nt++)
            w2v[nt] = *(const float4*)(w2 + n0 + wn + nt * 16 + quad * 4);
        #pragma unroll
        for (int mt = 0; mt < 4; mt++) {
            float s = 0.f;
            #pragma unroll
            for (int nt = 0; nt < 4; nt++) {
                s += fmaxf(acc[mt][nt][0], 0.f) * w2v[nt].x;
                s += fmaxf(acc[mt][nt][1], 0.f) * w2v[nt].y;
                s += fmaxf(acc[mt][nt][2], 0.f) * w2v[nt].z;
                s += fmaxf(acc[mt][nt][3], 0.f) * w2v[nt].w;
            }
            s += __shfl_down(s, 32);
            s += __shfl_down(s, 16);
            if (lane < 16) atomicAdd(&outp[m0 + wm + mt * 16 + lane], s);
        }
    } else {
        #pragma unroll
        for (int mt = 0; mt < 4; mt++) {
            size_t rowbase;
            if constexpr (MODE == 1) {
                int tok = perm_tile[wm + mt * 16 + tl];
                if (tok < 0) continue;
                rowbase = (size_t)tok * DIN;
            } else {
                rowbase = (size_t)(m0 + wm + mt * 16 + tl) * ldC;
            }
            #pragma unroll
            for (int nt = 0; nt < 4; nt++) {
                const int ncol = n0 + wn + nt * 16 + quad * 4;
                ushort4 o;
                if constexpr (MODE == 1) {
                    ushort4 rv = *(const ushort4*)(xres + rowbase + ncol);
                    o.x = f2bf(bf2f(rv.x) + fmaxf(acc[mt][nt][0], 0.f));
                    o.y = f2bf(bf2f(rv.y) + fmaxf(acc[mt][nt][1], 0.f));
                    o.z = f2bf(bf2f(rv.z) + fmaxf(acc[mt][nt][2], 0.f));
                    o.w = f2bf(bf2f(rv.w) + fmaxf(acc[mt][nt][3], 0.f));
                } else {
                    o.x = f2bf(fmaxf(acc[mt][nt][0], 0.f));
                    o.y = f2bf(fmaxf(acc[mt][nt][1], 0.f));
                    o.z = f2bf(fmaxf(acc[mt][nt][2], 0.f));
                    o.w = f2bf(fmaxf(acc[mt][nt][3], 0.f));
                }
                *(ushort4*)(C + rowbase + ncol) = o;
            }
        }
    }
}

extern "C" void kernel_launch(void* const* d_in, const int* in_sizes, int n_in,
                              void* d_out, int out_size, void* d_ws, size_t ws_size,
                              hipStream_t stream) {
    const float* x      = (const float*)d_in[0];
    const int*   types  = (const int*)d_in[1];
    const float* W_pre  = (const float*)d_in[2];
    const float* W_types= (const float*)d_in[3];
    const float* W_c1   = (const float*)d_in[4];
    const float* W_c2   = (const float*)d_in[5];
    float* out = (float*)d_out;

    // workspace layout:
    //  [0,32MB)    Xb   : x cast to bf16 [32768][512]; becomes X_res after GEMM2
    //  [32,96MB)   Xff  : x_ = relu(x@W_pre) bf16 [32768][1024]
    //  then transposed bf16 weights, perm, bucket offsets, counters
    char* ws = (char*)d_ws;
    unsigned short* Xb  = (unsigned short*)(ws);
    unsigned short* Xff = (unsigned short*)(ws + 33554432ull);
    unsigned short* WpT = (unsigned short*)(ws + 100663296ull);            // 1 MB
    unsigned short* WtT = (unsigned short*)(ws + 101711872ull);            // 8 MB
    unsigned short* WcT = (unsigned short*)(ws + 110100480ull);            // 0.5 MB
    int* perm           = (int*)(ws + 110624768ull);                        // MPAD ints
    int* po             = (int*)(ws + 110759936ull);                        // 9 ints
    int* fill           = po + 16;                                          // 8 ints
    int* cnt            = po + 32;                                          // 8 ints

    prep_weights_kernel<<<dim3(32, 32, 10), dim3(32, 8), 0, stream>>>(
        W_pre, W_types, W_c1, WpT, WtT, WcT, cnt);
    prep_tokens_kernel<<<N_TOK * DIN / 1024, 256, 0, stream>>>(x, Xb, types, cnt, perm);
    offsets_kernel<<<1, 64, 0, stream>>>(cnt, po, fill);
    scatter_kernel<<<N_TOK / 256, 256, 0, stream>>>(types, fill, perm, out);

    // GEMM1: Xff = relu(Xb @ W_pre)      [32768,512]x[512,1024]
    gemm_kernel<0><<<dim3(DFF / 256, N_TOK / 128), 512, 0, stream>>>(
        Xb, WpT, Xff, nullptr, nullptr, nullptr, nullptr, nullptr, 512, 512, 1024);
    // GEMM2 (routed): Xb = bf16(Xb + relu(Xff[perm] @ W_types[bucket]))
    gemm_kernel<1><<<dim3(DIN / 256, MPAD / 128), 512, 0, stream>>>(
        Xff, WtT, Xb, Xb, perm, po, nullptr, nullptr, 1024, 1024, 512);
    // GEMM3 + GEMV fused: out = relu(Xb @ W_c1) @ W_c2   (partial dots, atomicAdd)
    gemm_kernel<2><<<dim3(DIN / 256, N_TOK / 128), 512, 0, stream>>>(
        Xb, WcT, nullptr, nullptr, nullptr, nullptr, W_c2, out, 512, 512, 512);
}

// Round 5
// 279.538 us; speedup vs baseline: 1.6245x; 1.1206x over previous
//
#include <hip/hip_runtime.h>
#include <stdint.h>

// Problem constants (B=64, S=512 -> 32768 tokens)
#define N_TOK 32768
#define DIN   512
#define DFF   1024
#define MPAD  33792   // 32768 + 8*128 worst-case bucket padding

typedef __attribute__((ext_vector_type(8))) short bf16x8;
typedef __attribute__((ext_vector_type(4))) float f32x4;

__device__ __forceinline__ unsigned short f2bf(float f) {
    union { float f; unsigned int u; } v; v.f = f;
    unsigned int u = v.u;
    return (unsigned short)((u + 0x7FFFu + ((u >> 16) & 1u)) >> 16);
}
__device__ __forceinline__ float bf2f(unsigned int bits) {
    union { unsigned int u; float f; } v; v.u = bits << 16; return v.f;
}
// pack 4 floats -> 4 OCP e4m3 bytes (hw cvt, saturating)
__device__ __forceinline__ unsigned int pk4_fp8(float a, float b, float c, float d) {
    int v = __builtin_amdgcn_cvt_pk_fp8_f32(a, b, 0, false);
    v = __builtin_amdgcn_cvt_pk_fp8_f32(c, d, v, true);
    return (unsigned int)v;
}
__device__ __forceinline__ unsigned char f2fp8(float a) {
    return (unsigned char)(__builtin_amdgcn_cvt_pk_fp8_f32(a, a, 0, false) & 0xFF);
}

// async 16B global -> LDS (wave-uniform LDS base + lane*16 pattern)
__device__ __forceinline__ void async16(const void* g, void* l) {
    __builtin_amdgcn_global_load_lds(
        (const __attribute__((address_space(1))) void*)g,
        (__attribute__((address_space(3))) void*)l, 16, 0, 0);
}

// ---------------- fused weight prep ----------------
// z=0: W_pre [512][1024] -> Wp8 [1024][512] fp8 (x64)
// z=1..8: W_types[z-1] [1024][512] -> Wt8 [512][1024] fp8 (x64)
// z=9: W_c1 [512][512] -> WcT bf16 [512][512]
// also zeroes cnt[0..7] and fill2 (=cnt[8..15])
__global__ void prep_weights_kernel(const float* __restrict__ Wp,
                                    const float* __restrict__ Wt,
                                    const float* __restrict__ Wc,
                                    unsigned char* __restrict__ Wp8,
                                    unsigned char* __restrict__ Wt8,
                                    unsigned short* __restrict__ WcT,
                                    int* __restrict__ cnt) {
    __shared__ float tile[32][33];
    const int z = blockIdx.z;
    if (z == 0 && blockIdx.x == 0 && blockIdx.y == 0 &&
        threadIdx.y == 0 && threadIdx.x < 16)
        cnt[threadIdx.x] = 0;
    const float* s; int K, N;
    if (z == 0)      { s = Wp;                          K = 512;  N = 1024; }
    else if (z <= 8) { s = Wt + (size_t)(z-1)*DIN*DFF;  K = 1024; N = 512; }
    else             { s = Wc;                          K = 512;  N = 512; }
    const int n0 = blockIdx.x * 32, k0 = blockIdx.y * 32;
    if (n0 >= N || k0 >= K) return;
    for (int i = threadIdx.y; i < 32; i += 8)
        tile[i][threadIdx.x] = s[(size_t)(k0 + i) * N + n0 + threadIdx.x];
    __syncthreads();
    if (z == 0) {
        for (int i = threadIdx.y; i < 32; i += 8)
            Wp8[(size_t)(n0 + i) * K + k0 + threadIdx.x] = f2fp8(tile[threadIdx.x][i] * 64.f);
    } else if (z <= 8) {
        unsigned char* d = Wt8 + (size_t)(z-1)*DIN*DFF;
        for (int i = threadIdx.y; i < 32; i += 8)
            d[(size_t)(n0 + i) * K + k0 + threadIdx.x] = f2fp8(tile[threadIdx.x][i] * 64.f);
    } else {
        for (int i = threadIdx.y; i < 32; i += 8)
            WcT[(size_t)(n0 + i) * K + k0 + threadIdx.x] = f2bf(tile[threadIdx.x][i]);
    }
}

// ---------------- fused token prep: x -> bf16 Xb + fp8 Xb8, histogram, perm init --
__global__ void prep_tokens_kernel(const float* __restrict__ x,
                                   unsigned short* __restrict__ Xb,
                                   unsigned char* __restrict__ Xb8,
                                   const int* __restrict__ types,
                                   int* __restrict__ cnt,
                                   int* __restrict__ perm) {
    __shared__ int lc[8];
    const int blk = blockIdx.x, tid = threadIdx.x;
    const int i = blk * 1024 + tid * 4;
    float4 v = *(const float4*)(x + i);
    ushort4 o;
    o.x = f2bf(v.x); o.y = f2bf(v.y); o.z = f2bf(v.z); o.w = f2bf(v.w);
    *(ushort4*)(Xb + i) = o;
    *(unsigned int*)(Xb8 + i) = pk4_fp8(v.x, v.y, v.z, v.w);
    if (blk < 64) {
        if (tid < 8) lc[tid] = 0;
        __syncthreads();
        atomicAdd(&lc[types[blk * 512 + tid]], 1);
        atomicAdd(&lc[types[blk * 512 + 256 + tid]], 1);
        __syncthreads();
        if (tid < 8) atomicAdd(&cnt[tid], lc[tid]);
    } else if (blk < 64 + MPAD / 256) {
        perm[(blk - 64) * 256 + tid] = -1;
    }
}

// scatter token ids into buckets (prefix computed locally from cnt); zero out[]
__global__ void scatter_kernel(const int* __restrict__ types,
                               const int* __restrict__ cnt,
                               int* __restrict__ fill2,
                               int* __restrict__ perm,
                               float* __restrict__ outz) {
    int i = blockIdx.x * 256 + threadIdx.x;      // grid exactly covers N_TOK
    outz[i] = 0.f;
    int pob[8]; int off = 0;
    #pragma unroll
    for (int b = 0; b < 8; b++) { pob[b] = off; off += ((cnt[b] + 127) >> 7) << 7; }
    int lane = threadIdx.x & 63;
    unsigned long long lt = (1ull << lane) - 1ull;
    int t = types[i];
    #pragma unroll
    for (int b = 0; b < 8; b++) {
        unsigned long long m = __ballot(t == b);
        if (t == b) {
            int leader = __ffsll((unsigned long long)m) - 1;
            int base = 0;
            if (lane == leader) base = atomicAdd(&fill2[b], __popcll(m));
            base = __shfl(base, leader);
            perm[pob[b] + base + __popcll(m & lt)] = i;
        }
    }
}

// ---------- fp8 GEMM: 128x128 tile, BK=128, 256 thr / 4 waves, 16x16x32 fp8 -----
// LDS rows are 128B (32 banks); XOR swizzle on 16B chunks: slot j holds chunk
// j^(row&7) -> frag reads are 2-way max (free). D[n][tok] via swapped operands.
// MODE 0 (GEMM1): C = fp8(relu(acc) * 0.125)   [= 8*x_, acc carries x64 from W]
// MODE 1 (GEMM2): rows gathered via perm, B per bucket (prefix from cnt);
//                 C_bf16[tok] = bf16(xres_bf16[tok] + relu(acc)/512)
template <int MODE>
__global__ __launch_bounds__(256, 4)
void gemm_fp8_kernel(const unsigned char* __restrict__ A,
                     const unsigned char* __restrict__ B,
                     void* __restrict__ Cout,
                     const unsigned short* __restrict__ xres,
                     const int* __restrict__ perm,
                     const int* __restrict__ cnt,
                     int K, int ldA) {
    __shared__ unsigned char As[128 * 128];
    __shared__ unsigned char Bs[128 * 128];
    __shared__ int perm_tile[128];

    const int tid  = threadIdx.x;
    const int wave = tid >> 6;
    const int lane = tid & 63;
    const int quad = lane >> 4;
    const int tl   = lane & 15;
    const int m0 = blockIdx.y * 128;
    const int n0 = blockIdx.x * 128;
    const int wm = (wave & 1) * 64;
    const int wn = (wave >> 1) * 64;

    const unsigned char* Bp = B;
    if constexpr (MODE == 1) {
        int bsel = 0, total = 0;
        #pragma unroll
        for (int i = 0; i < 8; i++) {
            if (i > 0 && m0 >= total) bsel = i;   // total == po[i] at loop top
            total += ((cnt[i] + 127) >> 7) << 7;
        }
        if (m0 >= total) return;                  // fully-padded tail block
        Bp = B + (size_t)bsel * (DIN * DFF);
        if (tid < 128) perm_tile[tid] = perm[m0 + tid];
    }

    f32x4 acc[4][4];
    #pragma unroll
    for (int i = 0; i < 4; i++)
        #pragma unroll
        for (int j = 0; j < 4; j++)
            acc[i][j] = (f32x4){0.f, 0.f, 0.f, 0.f};

    for (int k0 = 0; k0 < K; k0 += 128) {
        __syncthreads();
        // A tile [128][128] fp8 = 1024 chunks of 16B, 4/thread, XOR-swizzled
        #pragma unroll
        for (int i = 0; i < 4; i++) {
            const int c   = (i * 4 + wave) * 64 + lane;
            const int row = c >> 3;
            const int gj  = (c & 7) ^ (row & 7);
            size_t arow;
            if constexpr (MODE == 1) {
                int tok = perm_tile[row];
                arow = (size_t)(tok < 0 ? 0 : tok);
            } else {
                arow = (size_t)(m0 + row);
            }
            async16(A + arow * ldA + k0 + gj * 16, (char*)As + (size_t)c * 16);
        }
        // B tile [128][128] fp8
        #pragma unroll
        for (int i = 0; i < 4; i++) {
            const int c   = (i * 4 + wave) * 64 + lane;
            const int row = c >> 3;
            const int gj  = (c & 7) ^ (row & 7);
            async16(Bp + (size_t)(n0 + row) * K + k0 + gj * 16, (char*)Bs + (size_t)c * 16);
        }
        __syncthreads();

        #pragma unroll
        for (int ks = 0; ks < 4; ks++) {
            long af[4], bfr[4];
            const int jc  = ks * 2 + (quad >> 1);    // logical 16B chunk in row
            const int sub = (quad & 1) * 8;          // 8B half of the chunk
            #pragma unroll
            for (int t = 0; t < 4; t++) {
                const int r = wm + t * 16 + tl;
                af[t] = *(const long*)(As + r * 128 + ((jc ^ (r & 7)) * 16) + sub);
            }
            #pragma unroll
            for (int t = 0; t < 4; t++) {
                const int r = wn + t * 16 + tl;
                bfr[t] = *(const long*)(Bs + r * 128 + ((jc ^ (r & 7)) * 16) + sub);
            }
            #pragma unroll
            for (int mt = 0; mt < 4; mt++)
                #pragma unroll
                for (int nt = 0; nt < 4; nt++)
                    acc[mt][nt] = __builtin_amdgcn_mfma_f32_16x16x32_fp8_fp8(
                        bfr[nt], af[mt], acc[mt][nt], 0, 0, 0);  // swapped: D[n][tok]
        }
    }

    // epilogue: lane holds 4 consecutive n (regs) for token tl
    if constexpr (MODE == 0) {
        unsigned char* C8 = (unsigned char*)Cout;
        #pragma unroll
        for (int mt = 0; mt < 4; mt++) {
            const size_t rowbase = (size_t)(m0 + wm + mt * 16 + tl) * DFF;
            #pragma unroll
            for (int nt = 0; nt < 4; nt++) {
                const int ncol = n0 + wn + nt * 16 + quad * 4;
                unsigned int p = pk4_fp8(fmaxf(acc[mt][nt][0], 0.f) * 0.125f,
                                         fmaxf(acc[mt][nt][1], 0.f) * 0.125f,
                                         fmaxf(acc[mt][nt][2], 0.f) * 0.125f,
                                         fmaxf(acc[mt][nt][3], 0.f) * 0.125f);
                *(unsigned int*)(C8 + rowbase + ncol) = p;
            }
        }
    } else {
        unsigned short* Cb = (unsigned short*)Cout;
        #pragma unroll
        for (int mt = 0; mt < 4; mt++) {
            int tok = perm_tile[wm + mt * 16 + tl];
            if (tok < 0) continue;
            const size_t rowbase = (size_t)tok * DIN;
            #pragma unroll
            for (int nt = 0; nt < 4; nt++) {
                const int ncol = n0 + wn + nt * 16 + quad * 4;
                ushort4 rv = *(const ushort4*)(xres + rowbase + ncol);
                ushort4 o;
                o.x = f2bf(bf2f(rv.x) + fmaxf(acc[mt][nt][0], 0.f) * 0.001953125f);
                o.y = f2bf(bf2f(rv.y) + fmaxf(acc[mt][nt][1], 0.f) * 0.001953125f);
                o.z = f2bf(bf2f(rv.z) + fmaxf(acc[mt][nt][2], 0.f) * 0.001953125f);
                o.w = f2bf(bf2f(rv.w) + fmaxf(acc[mt][nt][3], 0.f) * 0.001953125f);
                *(ushort4*)(Cb + rowbase + ncol) = o;
            }
        }
    }
}

// ------- bf16 GEMM3 + head (kept full precision): 128x256 tile, 512 thr --------
// out[tok] += relu(Xb @ W_c1) . w2   (atomicAdd partials per n-block)
__global__ __launch_bounds__(512, 4)
void gemm3_kernel(const unsigned short* __restrict__ A,
                  const unsigned short* __restrict__ B,
                  const float* __restrict__ w2,
                  float* __restrict__ outp,
                  int K, int ldA) {
    __shared__ unsigned short As[128 * 64];
    __shared__ unsigned short Bs[256 * 64];

    const int tid  = threadIdx.x;
    const int wave = tid >> 6;
    const int lane = tid & 63;
    const int quad = lane >> 4;
    const int tl   = lane & 15;
    const int m0 = blockIdx.y * 128;
    const int n0 = blockIdx.x * 256;
    const int wm = (wave & 1) * 64;
    const int wn = (wave >> 1) * 64;

    f32x4 acc[4][4];
    #pragma unroll
    for (int i = 0; i < 4; i++)
        #pragma unroll
        for (int j = 0; j < 4; j++)
            acc[i][j] = (f32x4){0.f, 0.f, 0.f, 0.f};

    for (int k0 = 0; k0 < K; k0 += 64) {
        __syncthreads();
        #pragma unroll
        for (int i = 0; i < 2; i++) {
            const int c   = (i * 8 + wave) * 64 + lane;
            const int row = c >> 3;
            const int gj  = (c & 7) ^ (row & 7);
            async16(A + (size_t)(m0 + row) * ldA + k0 + gj * 8, (char*)As + (size_t)c * 16);
        }
        #pragma unroll
        for (int i = 0; i < 4; i++) {
            const int c   = (i * 8 + wave) * 64 + lane;
            const int row = c >> 3;
            const int gj  = (c & 7) ^ (row & 7);
            async16(B + (size_t)(n0 + row) * K + k0 + gj * 8, (char*)Bs + (size_t)c * 16);
        }
        __syncthreads();

        #pragma unroll
        for (int ks = 0; ks < 2; ks++) {
            bf16x8 af[4], bfr[4];
            const int jc = ks * 4 + quad;
            #pragma unroll
            for (int t = 0; t < 4; t++) {
                const int r = wm + t * 16 + tl;
                af[t] = *(const bf16x8*)(As + (r * 8 + (jc ^ (r & 7))) * 8);
            }
            #pragma unroll
            for (int t = 0; t < 4; t++) {
                const int r = wn + t * 16 + tl;
                bfr[t] = *(const bf16x8*)(Bs + (r * 8 + (jc ^ (r & 7))) * 8);
            }
            #pragma unroll
            for (int mt = 0; mt < 4; mt++)
                #pragma unroll
                for (int nt = 0; nt < 4; nt++)
                    acc[mt][nt] = __builtin_amdgcn_mfma_f32_16x16x32_bf16(
                        bfr[nt], af[mt], acc[mt][nt], 0, 0, 0);
        }
    }

    float4 w2v[4];
    #pragma unroll
    for (int nt = 0; nt < 4; nt++)
        w2v[nt] = *(const float4*)(w2 + n0 + wn + nt * 16 + quad * 4);
    #pragma unroll
    for (int mt = 0; mt < 4; mt++) {
        float s = 0.f;
        #pragma unroll
        for (int nt = 0; nt < 4; nt++) {
            s += fmaxf(acc[mt][nt][0], 0.f) * w2v[nt].x;
            s += fmaxf(acc[mt][nt][1], 0.f) * w2v[nt].y;
            s += fmaxf(acc[mt][nt][2], 0.f) * w2v[nt].z;
            s += fmaxf(acc[mt][nt][3], 0.f) * w2v[nt].w;
        }
        s += __shfl_down(s, 32);
        s += __shfl_down(s, 16);
        if (lane < 16) atomicAdd(&outp[m0 + wm + mt * 16 + lane], s);
    }
}

extern "C" void kernel_launch(void* const* d_in, const int* in_sizes, int n_in,
                              void* d_out, int out_size, void* d_ws, size_t ws_size,
                              hipStream_t stream) {
    const float* x      = (const float*)d_in[0];
    const int*   types  = (const int*)d_in[1];
    const float* W_pre  = (const float*)d_in[2];
    const float* W_types= (const float*)d_in[3];
    const float* W_c1   = (const float*)d_in[4];
    const float* W_c2   = (const float*)d_in[5];
    float* out = (float*)d_out;

    // workspace layout (~87 MB):
    char* ws = (char*)d_ws;
    unsigned short* Xb  = (unsigned short*)(ws);                    // bf16 [32768][512], becomes X_res
    unsigned char*  Xff8= (unsigned char*)(ws + 33554432ull);       // fp8 [32768][1024] = 8*x_
    unsigned char*  Xb8 = (unsigned char*)(ws + 67108864ull);       // fp8 [32768][512] = x
    unsigned char*  Wp8 = (unsigned char*)(ws + 83886080ull);       // fp8 [1024][512] (x64)
    unsigned char*  Wt8 = (unsigned char*)(ws + 84410368ull);       // fp8 [8][512][1024] (x64)
    unsigned short* WcT = (unsigned short*)(ws + 88604672ull);      // bf16 [512][512]
    int* perm           = (int*)(ws + 89128960ull);                  // MPAD ints
    int* cnt            = (int*)(ws + 89264128ull);                  // cnt[8], fill2 = cnt+8
    int* fill2          = cnt + 8;

    prep_weights_kernel<<<dim3(32, 32, 10), dim3(32, 8), 0, stream>>>(
        W_pre, W_types, W_c1, Wp8, Wt8, WcT, cnt);
    prep_tokens_kernel<<<N_TOK * DIN / 1024, 256, 0, stream>>>(x, Xb, Xb8, types, cnt, perm);
    scatter_kernel<<<N_TOK / 256, 256, 0, stream>>>(types, cnt, fill2, perm, out);

    // GEMM1 (fp8): Xff8 = fp8(8 * relu(x @ W_pre))   [32768,512]x[512,1024]
    gemm_fp8_kernel<0><<<dim3(DFF / 128, N_TOK / 128), 256, 0, stream>>>(
        Xb8, Wp8, Xff8, nullptr, nullptr, nullptr, 512, 512);
    // GEMM2 (fp8, routed): Xb = bf16(Xb + relu(Xff8[perm] @ Wt8[bucket]) / 512)
    gemm_fp8_kernel<1><<<dim3(DIN / 128, MPAD / 128), 256, 0, stream>>>(
        Xff8, Wt8, Xb, Xb, perm, cnt, 1024, 1024);
    // GEMM3 + head (bf16): out = relu(Xb @ W_c1) @ W_c2
    gemm3_kernel<<<dim3(DIN / 256, N_TOK / 128), 512, 0, stream>>>(
        Xb, WcT, W_c2, out, 512, 512);
}